// Round 4
// baseline (275.463 us; speedup 1.0000x reference)
//
#include <hip/hip_runtime.h>
#include <hip/hip_bf16.h>

constexpr int Nb    = 16;
constexpr int Mdim  = 2048;
constexpr int FINC  = 16;
constexpr int KORD  = 6;
constexpr int FOUTC = 128;

typedef __attribute__((ext_vector_type(8))) short bf16x8;
typedef __attribute__((ext_vector_type(4))) float f32x4;

__device__ __forceinline__ unsigned short f2b(float f) {
  unsigned int u = __float_as_uint(f);
  u += 0x7FFFu + ((u >> 16) & 1u);      // round-to-nearest-even
  return (unsigned short)(u >> 16);
}

// Transpose x[n][m][f] f32 -> xt_f[n][f][m] f32 and xt_b[n][f][m] bf16.
__global__ __launch_bounds__(256)
void prep_kernel(const float* __restrict__ x,
                 float* __restrict__ xt_f,
                 unsigned short* __restrict__ xt_b) {
  const int n = blockIdx.x >> 4, f = blockIdx.x & 15;
  for (int m = threadIdx.x; m < Mdim; m += 256) {
    const float v = x[((size_t)n * Mdim + m) * FINC + f];
    const size_t o = ((size_t)n * FINC + f) * Mdim + m;
    xt_f[o] = v;
    xt_b[o] = f2b(v);
  }
}

// One Chebyshev pass via MFMA.
// MODE 0: compute from bf16 Lb (fragment gather, L3-resident).
// MODE 1: phase A = coalesced convert of this block's 32-row L panel
//         (f32 -> bf16 Lb, sequential streams), then compute from Lb
//         (gather hits own-XCD L2). Used for pass 1.
// MODE 2: fallback, fragment-gather straight from f32 L (no Lb store).
// 2-way K-split: tile (16 rows) x 2 waves (k halves), LDS combine.
//   A = Tprev^T (16 x K) from At (bf16, [n][16][2048])
//   B = L rows  (K x 16)
// Output transposed: Tf/Tb [n][16][2048]; val = FIRST ? Y : 2Y - P2t.
template<int MODE, bool FIRST>
__global__ __launch_bounds__(256, 4)
void cheb_mfma(const float* __restrict__ Lf,
               const unsigned short* __restrict__ Lb,
               unsigned short* __restrict__ LbOut,
               const unsigned short* __restrict__ At,
               const float* __restrict__ P2t,
               float* __restrict__ Tf,
               unsigned short* __restrict__ Tb) {
  constexpr int UNR = (MODE == 2) ? 4 : 8;
  const int tid  = threadIdx.x;
  const int wave = tid >> 6;
  const int lane = tid & 63;
  const int tile = wave >> 1;          // 2 tiles per block
  const int kh   = wave & 1;           // k-half
  const int n    = blockIdx.x >> 6;                      // 64 blocks per n
  const int rowp = (blockIdx.x & 63) * 32;               // block's 32-row panel
  const int row0 = rowp + tile * 16;                     // 16-row tile
  const int lr   = lane & 15;   // D col = L-row offset; A row (f) for loads
  const int g    = lane >> 4;   // k-group

  if (MODE == 1) {
    // ---- phase A: coalesced panel convert (32 rows x 2048) ----
    const size_t pb = ((size_t)n * Mdim + rowp) * Mdim;
    #pragma unroll 4
    for (int u = tid; u < 32 * (Mdim / 4); u += 256) {
      const int r  = u >> 9;          // u / 512
      const int c4 = u & 511;
      const size_t gi = pb + (size_t)r * Mdim + c4 * 4;
      const float4 lv = *reinterpret_cast<const float4*>(Lf + gi);
      ushort4 b;
      b.x = f2b(lv.x); b.y = f2b(lv.y); b.z = f2b(lv.z); b.w = f2b(lv.w);
      *reinterpret_cast<ushort4*>(LbOut + gi) = b;
    }
    __syncthreads();   // writes visible block-wide (same CU/L2)
  }

  const unsigned short* Lsrc = (MODE == 1) ? LbOut : Lb;
  const size_t Lrow  = ((size_t)n * Mdim + row0 + lr) * Mdim;
  const size_t Abase = ((size_t)n * FINC + lr) * Mdim;
  const int kbase = kh * (Mdim / 2);

  f32x4 acc = {0.f, 0.f, 0.f, 0.f};

  for (int k0 = kbase; k0 < kbase + Mdim / 2; k0 += 32 * UNR) {
    #pragma unroll
    for (int uu = 0; uu < UNR; ++uu) {
      const int ka = k0 + uu * 32 + g * 8;

      // A fragment: Tprev^T[f=lr][ka..ka+8)  (L1/L2-hot)
      bf16x8 a = *reinterpret_cast<const bf16x8*>(At + Abase + ka);

      // B fragment: L[row0+lr][ka..ka+8)
      bf16x8 b;
      if (MODE == 2) {
        f32x4 lo = *reinterpret_cast<const f32x4*>(Lf + Lrow + ka);
        f32x4 hi = *reinterpret_cast<const f32x4*>(Lf + Lrow + ka + 4);
        b[0] = (short)f2b(lo.x); b[1] = (short)f2b(lo.y);
        b[2] = (short)f2b(lo.z); b[3] = (short)f2b(lo.w);
        b[4] = (short)f2b(hi.x); b[5] = (short)f2b(hi.y);
        b[6] = (short)f2b(hi.z); b[7] = (short)f2b(hi.w);
      } else {
        b = *reinterpret_cast<const bf16x8*>(Lsrc + Lrow + ka);
      }

      acc = __builtin_amdgcn_mfma_f32_16x16x32_bf16(a, b, acc, 0, 0, 0);
    }
  }

  // combine the two k-halves
  __shared__ f32x4 part[2][64];
  if (kh == 1) part[tile][lane] = acc;
  __syncthreads();
  if (kh == 0) {
    const f32x4 o = part[tile][lane];
    // D layout (m89-verified): col = lane&15, row = (lane>>4)*4 + r.
    #pragma unroll
    for (int r = 0; r < 4; ++r) {
      const int f = g * 4 + r;
      const size_t oi = ((size_t)n * FINC + f) * Mdim + row0 + lr;
      float v = acc[r] + o[r];
      v = FIRST ? v : 2.f * v - P2t[oi];
      Tf[oi] = v;
      Tb[oi] = f2b(v);
    }
  }
}

// Epilogue: out = relu(feat @ W + B); feat[n*m][f*6+kk] = T_kk^T[n][f][m]
constexpr int EROWS = 32;
struct EpiSmem {
  float W[KORD * FINC][FOUTC];          // 49152 B
  float feat[EROWS][KORD * FINC + 1];   // 12416 B
  float B[FOUTC];                       // 512 B
};

__global__ __launch_bounds__(256)
void epilogue_kernel(const float* __restrict__ xt,     // [n][16][2048] f32
                     const float* __restrict__ Tws,    // T1..T5, stride TSZ
                     const float* __restrict__ Wg,
                     const float* __restrict__ Bg,
                     float* __restrict__ out) {
  __shared__ EpiSmem sm;
  const int tid = threadIdx.x;
  const int n       = blockIdx.x >> 6;
  const int rowbase = (blockIdx.x & 63) * EROWS;
  constexpr size_t TSZ = (size_t)Nb * Mdim * FINC;

  for (int u = tid; u < (KORD * FINC * FOUTC) / 4; u += 256) {
    const int fi = u >> 5, fo4 = u & 31;
    *reinterpret_cast<float4*>(&sm.W[fi][fo4 * 4]) =
        *reinterpret_cast<const float4*>(&Wg[fi * FOUTC + fo4 * 4]);
  }
  if (tid < FOUTC / 4) {
    *reinterpret_cast<float4*>(&sm.B[tid * 4]) =
        *reinterpret_cast<const float4*>(&Bg[tid * 4]);
  }
  #pragma unroll
  for (int kk = 0; kk < KORD; ++kk) {
    const float* src = (kk == 0) ? xt : (Tws + (size_t)(kk - 1) * TSZ);
    for (int u = tid; u < EROWS * FINC; u += 256) {
      const int r = u & 31, f = u >> 5;     // r consecutive -> coalesced
      sm.feat[r][f * KORD + kk] =
          src[((size_t)n * FINC + f) * Mdim + rowbase + r];
    }
  }
  __syncthreads();

  const int row = tid & 31;
  const int fo8 = tid >> 5;
  float acc[16];
  #pragma unroll
  for (int q = 0; q < 16; ++q) acc[q] = sm.B[fo8 * 16 + q];

  #pragma unroll 4
  for (int fi = 0; fi < KORD * FINC; ++fi) {
    const float fv = sm.feat[row][fi];
    #pragma unroll
    for (int q = 0; q < 4; ++q) {
      float4 wv = *reinterpret_cast<const float4*>(&sm.W[fi][fo8 * 16 + q * 4]);
      acc[q * 4]     = fmaf(fv, wv.x, acc[q * 4]);
      acc[q * 4 + 1] = fmaf(fv, wv.y, acc[q * 4 + 1]);
      acc[q * 4 + 2] = fmaf(fv, wv.z, acc[q * 4 + 2]);
      acc[q * 4 + 3] = fmaf(fv, wv.w, acc[q * 4 + 3]);
    }
  }

  const size_t obase = ((size_t)n * Mdim + rowbase + row) * FOUTC + fo8 * 16;
  #pragma unroll
  for (int q = 0; q < 4; ++q) {
    float4 ov;
    ov.x = fmaxf(acc[q * 4], 0.f);
    ov.y = fmaxf(acc[q * 4 + 1], 0.f);
    ov.z = fmaxf(acc[q * 4 + 2], 0.f);
    ov.w = fmaxf(acc[q * 4 + 3], 0.f);
    *reinterpret_cast<float4*>(&out[obase + q * 4]) = ov;
  }
}

extern "C" void kernel_launch(void* const* d_in, const int* in_sizes, int n_in,
                              void* d_out, int out_size, void* d_ws, size_t ws_size,
                              hipStream_t stream) {
  const float* x = (const float*)d_in[0];
  const float* L = (const float*)d_in[1];
  const float* W = (const float*)d_in[2];
  const float* B = (const float*)d_in[3];
  float* out = (float*)d_out;

  constexpr size_t TSZ      = (size_t)Nb * Mdim * FINC;     // 524288 elems
  constexpr size_t LB_ELEMS = (size_t)Nb * Mdim * Mdim;
  const size_t need_full = LB_ELEMS * 2 + TSZ * 4 * 6 + TSZ * 2 * 6;  // ~152 MB
  const bool lb = ws_size >= need_full;

  char* p = (char*)d_ws;
  unsigned short* Lbuf = (unsigned short*)p;
  if (lb) p += LB_ELEMS * 2;
  float* xt_f = (float*)p;            p += TSZ * 4;
  float* T1f  = (float*)p;            p += TSZ * 4 * 5;
  unsigned short* xt_b = (unsigned short*)p;  p += TSZ * 2;
  unsigned short* T1b  = (unsigned short*)p;

  float*          Tf[5] = {T1f, T1f + TSZ, T1f + 2 * TSZ, T1f + 3 * TSZ, T1f + 4 * TSZ};
  unsigned short* Tb[5] = {T1b, T1b + TSZ, T1b + 2 * TSZ, T1b + 3 * TSZ, T1b + 4 * TSZ};

  dim3 blk(256);
  hipLaunchKernelGGL(prep_kernel, dim3(Nb * FINC), blk, 0, stream, x, xt_f, xt_b);

  dim3 grid(Nb * 64);   // 1024 blocks: 2 tiles/block x 2 k-half waves
  if (lb) {
    hipLaunchKernelGGL((cheb_mfma<1, true>), grid, blk, 0, stream,
                       L, nullptr, Lbuf, xt_b, nullptr, Tf[0], Tb[0]);
    hipLaunchKernelGGL((cheb_mfma<0, false>), grid, blk, 0, stream,
                       nullptr, Lbuf, nullptr, Tb[0], xt_f, Tf[1], Tb[1]);
    hipLaunchKernelGGL((cheb_mfma<0, false>), grid, blk, 0, stream,
                       nullptr, Lbuf, nullptr, Tb[1], Tf[0], Tf[2], Tb[2]);
    hipLaunchKernelGGL((cheb_mfma<0, false>), grid, blk, 0, stream,
                       nullptr, Lbuf, nullptr, Tb[2], Tf[1], Tf[3], Tb[3]);
    hipLaunchKernelGGL((cheb_mfma<0, false>), grid, blk, 0, stream,
                       nullptr, Lbuf, nullptr, Tb[3], Tf[2], Tf[4], Tb[4]);
  } else {
    hipLaunchKernelGGL((cheb_mfma<2, true>), grid, blk, 0, stream,
                       L, nullptr, nullptr, xt_b, nullptr, Tf[0], Tb[0]);
    hipLaunchKernelGGL((cheb_mfma<2, false>), grid, blk, 0, stream,
                       L, nullptr, nullptr, Tb[0], xt_f, Tf[1], Tb[1]);
    hipLaunchKernelGGL((cheb_mfma<2, false>), grid, blk, 0, stream,
                       L, nullptr, nullptr, Tb[1], Tf[0], Tf[2], Tb[2]);
    hipLaunchKernelGGL((cheb_mfma<2, false>), grid, blk, 0, stream,
                       L, nullptr, nullptr, Tb[2], Tf[1], Tf[3], Tb[3]);
    hipLaunchKernelGGL((cheb_mfma<2, false>), grid, blk, 0, stream,
                       L, nullptr, nullptr, Tb[3], Tf[2], Tf[4], Tb[4]);
  }

  hipLaunchKernelGGL(epilogue_kernel, dim3(Nb * (Mdim / EROWS)), blk, 0, stream,
                     xt_f, T1f, W, B, out);
}

// Round 5
// 238.705 us; speedup vs baseline: 1.1540x; 1.1540x over previous
//
#include <hip/hip_runtime.h>
#include <hip/hip_bf16.h>

constexpr int Nb    = 16;
constexpr int Mdim  = 2048;
constexpr int FINC  = 16;
constexpr int KORD  = 6;
constexpr int FOUTC = 128;
constexpr int NSTEP = Mdim / 32;   // 64 k-steps
constexpr int NRT   = Mdim / 16;   // 128 row tiles

typedef __attribute__((ext_vector_type(8))) short bf16x8;
typedef __attribute__((ext_vector_type(4))) float f32x4;

__device__ __forceinline__ unsigned short f2b(float f) {
  unsigned int u = __float_as_uint(f);
  u += 0x7FFFu + ((u >> 16) & 1u);      // round-to-nearest-even
  return (unsigned short)(u >> 16);
}
__device__ __forceinline__ f32x4 ldnt4(const float* p) {
  return __builtin_nontemporal_load(reinterpret_cast<const f32x4*>(p));
}

// xt_f[n][f][m] = x[n][m][f]  (f32 linear; used as P2 of pass 2 and by epilogue)
__global__ __launch_bounds__(256)
void prep_lin(const float* __restrict__ x, float* __restrict__ xt_f) {
  const int n = blockIdx.x >> 4, f = blockIdx.x & 15;
  for (int m = threadIdx.x; m < Mdim; m += 256) {
    xt_f[((size_t)n * FINC + f) * Mdim + m] =
        x[((size_t)n * Mdim + m) * FINC + f];
  }
}

// xswz: x^T in MFMA A-fragment order.
// fragment(s, lane, j) = x^T[f = lane&15][m = s*32 + (lane>>4)*8 + j]
__global__ __launch_bounds__(256)
void prep_swz(const float* __restrict__ x, unsigned short* __restrict__ xswz) {
  const int n = blockIdx.x;
  const int lane = threadIdx.x & 63, w4 = threadIdx.x >> 6;
  for (int s = w4; s < NSTEP; s += 4) {
    const int m0 = s * 32 + (lane >> 4) * 8;
    const int f  = lane & 15;
    bf16x8 frag;
    #pragma unroll
    for (int j = 0; j < 8; ++j)
      frag[j] = (short)f2b(x[((size_t)n * Mdim + m0 + j) * FINC + f]);
    *reinterpret_cast<bf16x8*>(xswz + ((size_t)n * NSTEP + s) * 512 + lane * 8) = frag;
  }
}

// One Chebyshev pass via MFMA; all hot-loop loads coalesced.
// MODE 0: B from LbSwz (bf16 fragment layout, contiguous streams).
// MODE 1: B gathered from f32 L (nontemporal), fragment stored to LbSwz_w.
// MODE 2: B gathered from f32 L, no store (fallback).
// A always from Aswz (fragment layout, L2-hot).
// 2 tiles/block x 2 k-half waves; halves combined via LDS.
// Output: Tf linear [n][16][2048] f32; if WRITEA, next A (Tswz) via LDS transpose.
template<int MODE, bool FIRST, bool WRITEA>
__global__ __launch_bounds__(256, 4)
void cheb_mfma(const float* __restrict__ Lf,
               const unsigned short* __restrict__ LbSwz_r,
               unsigned short* __restrict__ LbSwz_w,
               const unsigned short* __restrict__ Aswz,
               const float* __restrict__ P2t,
               float* __restrict__ Tf,
               unsigned short* __restrict__ Aswz_next) {
  constexpr int UNR = (MODE == 0) ? 8 : 4;
  const int tid  = threadIdx.x;
  const int wave = tid >> 6;
  const int lane = tid & 63;
  const int tile = wave >> 1;          // 2 tiles per block
  const int kh   = wave & 1;           // k-half
  const int n    = blockIdx.x >> 6;                      // 64 blocks per n
  const int panel = blockIdx.x & 63;                     // 32-row panel = s_out
  const int rt   = panel * 2 + tile;                     // 16-row tile index
  const int row0 = rt * 16;
  const int lr   = lane & 15;
  const int g    = lane >> 4;

  const unsigned short* Ap = Aswz + ((size_t)n * NSTEP + kh * 32) * 512 + lane * 8;
  const size_t Bfrag = (((size_t)n * NRT + rt) * NSTEP + kh * 32) * 512 + lane * 8;
  const size_t Lrow  = ((size_t)n * Mdim + row0 + lr) * Mdim;

  f32x4 acc = {0.f, 0.f, 0.f, 0.f};

  for (int jj = 0; jj < 32; jj += UNR) {
    #pragma unroll
    for (int uu = 0; uu < UNR; ++uu) {
      const int sl = jj + uu;                 // local k-step in this half
      bf16x8 a = *reinterpret_cast<const bf16x8*>(Ap + (size_t)sl * 512);
      bf16x8 b;
      if (MODE == 0) {
        b = *reinterpret_cast<const bf16x8*>(LbSwz_r + Bfrag + (size_t)sl * 512);
      } else {
        const int ka = (kh * 32 + sl) * 32 + g * 8;
        f32x4 lo = ldnt4(Lf + Lrow + ka);
        f32x4 hi = ldnt4(Lf + Lrow + ka + 4);
        b[0] = (short)f2b(lo.x); b[1] = (short)f2b(lo.y);
        b[2] = (short)f2b(lo.z); b[3] = (short)f2b(lo.w);
        b[4] = (short)f2b(hi.x); b[5] = (short)f2b(hi.y);
        b[6] = (short)f2b(hi.z); b[7] = (short)f2b(hi.w);
        if (MODE == 1)
          *reinterpret_cast<bf16x8*>(LbSwz_w + Bfrag + (size_t)sl * 512) = b;
      }
      acc = __builtin_amdgcn_mfma_f32_16x16x32_bf16(a, b, acc, 0, 0, 0);
    }
  }

  // combine the two k-halves; stage output tile for the A-swizzle write
  __shared__ f32x4 part[2][64];
  __shared__ float Tt[32][17];
  if (kh == 1) part[tile][lane] = acc;
  __syncthreads();
  if (kh == 0) {
    const f32x4 o = part[tile][lane];
    // D layout (m89-verified): col = lane&15, row = (lane>>4)*4 + r  (row = f here)
    #pragma unroll
    for (int r = 0; r < 4; ++r) {
      const int f = g * 4 + r;
      const size_t oi = ((size_t)n * FINC + f) * Mdim + row0 + lr;
      float v = acc[r] + o[r];
      if constexpr (!FIRST) v = 2.f * v - P2t[oi];
      Tf[oi] = v;
      if (WRITEA) Tt[tile * 16 + lr][f] = v;
    }
  }
  if constexpr (WRITEA) {
    __syncthreads();
    if (wave == 0) {
      // fragment(s_out, lane, j) = T^T[f=lane&15][m = panel*32 + (lane>>4)*8 + j]
      bf16x8 frag;
      #pragma unroll
      for (int j = 0; j < 8; ++j)
        frag[j] = (short)f2b(Tt[(lane >> 4) * 8 + j][lane & 15]);
      *reinterpret_cast<bf16x8*>(
          Aswz_next + ((size_t)n * NSTEP + panel) * 512 + lane * 8) = frag;
    }
  }
}

// Epilogue: out = relu(feat @ W + B); feat[n*m][f*6+kk] = T_kk^T[n][f][m]
constexpr int EROWS = 32;
struct EpiSmem {
  float W[KORD * FINC][FOUTC];          // 49152 B
  float feat[EROWS][KORD * FINC + 1];   // 12416 B
  float B[FOUTC];                       // 512 B
};

__global__ __launch_bounds__(256)
void epilogue_kernel(const float* __restrict__ xt,     // [n][16][2048] f32
                     const float* __restrict__ Tws,    // T1..T5, stride TSZ
                     const float* __restrict__ Wg,
                     const float* __restrict__ Bg,
                     float* __restrict__ out) {
  __shared__ EpiSmem sm;
  const int tid = threadIdx.x;
  const int n       = blockIdx.x >> 6;
  const int rowbase = (blockIdx.x & 63) * EROWS;
  constexpr size_t TSZ = (size_t)Nb * Mdim * FINC;

  for (int u = tid; u < (KORD * FINC * FOUTC) / 4; u += 256) {
    const int fi = u >> 5, fo4 = u & 31;
    *reinterpret_cast<float4*>(&sm.W[fi][fo4 * 4]) =
        *reinterpret_cast<const float4*>(&Wg[fi * FOUTC + fo4 * 4]);
  }
  if (tid < FOUTC / 4) {
    *reinterpret_cast<float4*>(&sm.B[tid * 4]) =
        *reinterpret_cast<const float4*>(&Bg[tid * 4]);
  }
  #pragma unroll
  for (int kk = 0; kk < KORD; ++kk) {
    const float* src = (kk == 0) ? xt : (Tws + (size_t)(kk - 1) * TSZ);
    for (int u = tid; u < EROWS * FINC; u += 256) {
      const int r = u & 31, f = u >> 5;     // r consecutive -> coalesced
      sm.feat[r][f * KORD + kk] =
          src[((size_t)n * FINC + f) * Mdim + rowbase + r];
    }
  }
  __syncthreads();

  const int row = tid & 31;
  const int fo8 = tid >> 5;
  float acc[16];
  #pragma unroll
  for (int q = 0; q < 16; ++q) acc[q] = sm.B[fo8 * 16 + q];

  #pragma unroll 4
  for (int fi = 0; fi < KORD * FINC; ++fi) {
    const float fv = sm.feat[row][fi];
    #pragma unroll
    for (int q = 0; q < 4; ++q) {
      float4 wv = *reinterpret_cast<const float4*>(&sm.W[fi][fo8 * 16 + q * 4]);
      acc[q * 4]     = fmaf(fv, wv.x, acc[q * 4]);
      acc[q * 4 + 1] = fmaf(fv, wv.y, acc[q * 4 + 1]);
      acc[q * 4 + 2] = fmaf(fv, wv.z, acc[q * 4 + 2]);
      acc[q * 4 + 3] = fmaf(fv, wv.w, acc[q * 4 + 3]);
    }
  }

  const size_t obase = ((size_t)n * Mdim + rowbase + row) * FOUTC + fo8 * 16;
  #pragma unroll
  for (int q = 0; q < 4; ++q) {
    float4 ov;
    ov.x = fmaxf(acc[q * 4], 0.f);
    ov.y = fmaxf(acc[q * 4 + 1], 0.f);
    ov.z = fmaxf(acc[q * 4 + 2], 0.f);
    ov.w = fmaxf(acc[q * 4 + 3], 0.f);
    *reinterpret_cast<float4*>(&out[obase + q * 4]) = ov;
  }
}

extern "C" void kernel_launch(void* const* d_in, const int* in_sizes, int n_in,
                              void* d_out, int out_size, void* d_ws, size_t ws_size,
                              hipStream_t stream) {
  const float* x = (const float*)d_in[0];
  const float* L = (const float*)d_in[1];
  const float* W = (const float*)d_in[2];
  const float* B = (const float*)d_in[3];
  float* out = (float*)d_out;

  constexpr size_t TSZ      = (size_t)Nb * Mdim * FINC;     // 524288 elems
  constexpr size_t LB_ELEMS = (size_t)Nb * Mdim * Mdim;
  const size_t need_full = LB_ELEMS * 2 + TSZ * 4 * 6 + TSZ * 2 * 6;  // ~152 MB
  const bool lb = ws_size >= need_full;

  char* p = (char*)d_ws;
  unsigned short* Lbuf = (unsigned short*)p;   // fragment-order bf16 L
  if (lb) p += LB_ELEMS * 2;
  float* xt_f = (float*)p;            p += TSZ * 4;
  float* T1f  = (float*)p;            p += TSZ * 4 * 5;
  unsigned short* xswz = (unsigned short*)p;  p += TSZ * 2;
  unsigned short* Tswz = (unsigned short*)p;  // 5 buffers of TSZ shorts

  float*          Tf[5] = {T1f, T1f + TSZ, T1f + 2 * TSZ, T1f + 3 * TSZ, T1f + 4 * TSZ};
  unsigned short* Ts[5] = {Tswz, Tswz + TSZ, Tswz + 2 * TSZ, Tswz + 3 * TSZ, Tswz + 4 * TSZ};

  dim3 blk(256);
  hipLaunchKernelGGL(prep_lin, dim3(Nb * FINC), blk, 0, stream, x, xt_f);
  hipLaunchKernelGGL(prep_swz, dim3(Nb), blk, 0, stream, x, xswz);

  dim3 grid(Nb * 64);   // 1024 blocks: 2 tiles/block x 2 k-half waves
  if (lb) {
    hipLaunchKernelGGL((cheb_mfma<1, true, true>), grid, blk, 0, stream,
                       L, nullptr, Lbuf, xswz, nullptr, Tf[0], Ts[0]);
    hipLaunchKernelGGL((cheb_mfma<0, false, true>), grid, blk, 0, stream,
                       nullptr, Lbuf, nullptr, Ts[0], xt_f, Tf[1], Ts[1]);
    hipLaunchKernelGGL((cheb_mfma<0, false, true>), grid, blk, 0, stream,
                       nullptr, Lbuf, nullptr, Ts[1], Tf[0], Tf[2], Ts[2]);
    hipLaunchKernelGGL((cheb_mfma<0, false, true>), grid, blk, 0, stream,
                       nullptr, Lbuf, nullptr, Ts[2], Tf[1], Tf[3], Ts[3]);
    hipLaunchKernelGGL((cheb_mfma<0, false, false>), grid, blk, 0, stream,
                       nullptr, Lbuf, nullptr, Ts[3], Tf[2], Tf[4], nullptr);
  } else {
    hipLaunchKernelGGL((cheb_mfma<2, true, true>), grid, blk, 0, stream,
                       L, nullptr, nullptr, xswz, nullptr, Tf[0], Ts[0]);
    hipLaunchKernelGGL((cheb_mfma<2, false, true>), grid, blk, 0, stream,
                       L, nullptr, nullptr, Ts[0], xt_f, Tf[1], Ts[1]);
    hipLaunchKernelGGL((cheb_mfma<2, false, true>), grid, blk, 0, stream,
                       L, nullptr, nullptr, Ts[1], Tf[0], Tf[2], Ts[2]);
    hipLaunchKernelGGL((cheb_mfma<2, false, true>), grid, blk, 0, stream,
                       L, nullptr, nullptr, Ts[2], Tf[1], Tf[3], Ts[3]);
    hipLaunchKernelGGL((cheb_mfma<2, false, false>), grid, blk, 0, stream,
                       L, nullptr, nullptr, Ts[3], Tf[2], Tf[4], nullptr);
  }

  hipLaunchKernelGGL(epilogue_kernel, dim3(Nb * (Mdim / EROWS)), blk, 0, stream,
                     xt_f, T1f, W, B, out);
}

// Round 7
// 224.985 us; speedup vs baseline: 1.2244x; 1.0610x over previous
//
#include <hip/hip_runtime.h>
#include <hip/hip_bf16.h>

constexpr int Nb    = 16;
constexpr int Mdim  = 2048;
constexpr int FINC  = 16;
constexpr int KORD  = 6;
constexpr int FOUTC = 128;
constexpr int NSTEP = Mdim / 32;   // 64 k-steps
constexpr int NRT   = Mdim / 16;   // 128 row tiles
constexpr size_t TSZ = (size_t)Nb * Mdim * FINC;

typedef __attribute__((ext_vector_type(8))) short bf16x8;
typedef __attribute__((ext_vector_type(4))) float f32x4;

__device__ __forceinline__ unsigned short f2b(float f) {
  unsigned int u = __float_as_uint(f);
  u += 0x7FFFu + ((u >> 16) & 1u);      // round-to-nearest-even
  return (unsigned short)(u >> 16);
}
__device__ __forceinline__ f32x4 ldnt4(const float* p) {
  return __builtin_nontemporal_load(reinterpret_cast<const f32x4*>(p));
}

// xt_f[n][f][m] = x[n][m][f]  (f32 linear; P2 of pass 2, epilogue input)
__global__ __launch_bounds__(256)
void prep_lin(const float* __restrict__ x, float* __restrict__ xt_f) {
  const int n = blockIdx.x >> 4, f = blockIdx.x & 15;
  for (int m = threadIdx.x; m < Mdim; m += 256)
    xt_f[((size_t)n * FINC + f) * Mdim + m] = x[((size_t)n * Mdim + m) * FINC + f];
}

// xswz: x^T in MFMA A-fragment order.
// fragment(s, lane, j) = x^T[f = lane&15][m = s*32 + (lane>>4)*8 + j]
__global__ __launch_bounds__(256)
void prep_swz(const float* __restrict__ x, unsigned short* __restrict__ xswz) {
  const int n = blockIdx.x;
  const int lane = threadIdx.x & 63, w4 = threadIdx.x >> 6;
  for (int s = w4; s < NSTEP; s += 4) {
    const int mb = s * 32 + (lane >> 4) * 8;
    const int f  = lane & 15;
    bf16x8 frag;
    #pragma unroll
    for (int j = 0; j < 8; ++j)
      frag[j] = (short)f2b(x[((size_t)n * Mdim + mb + j) * FINC + f]);
    *reinterpret_cast<bf16x8*>(xswz + ((size_t)n * NSTEP + s) * 512 + lane * 8) = frag;
  }
}

struct ConvSmem {
  unsigned short cvt[32][264];   // 16896 B: 32-row x 256-col bf16 chunk (padded)
  f32x4 part[2][64];             // 4096 B : k-half combine
  float Tt[32][17];              // 2176 B : T1 tile transpose
};

// Convert this block's 32-row L panel to fragment-order bf16 Lb
// (coalesced nontemporal f32 reads -> LDS -> coalesced 1KB frag stores)
// AND compute pass 1 (T1 = L x) from the staged chunks.
// Normal launch — no cooperative anything.
__global__ __launch_bounds__(256, 4)
void conv_pass1(const float* __restrict__ Lf,
                unsigned short* __restrict__ Lb,
                const unsigned short* __restrict__ xswz,
                float* __restrict__ T1f,
                unsigned short* __restrict__ T1swz) {
  __shared__ ConvSmem sm;
  const int tid  = threadIdx.x;
  const int wave = tid >> 6;
  const int lane = tid & 63;
  const int lr   = lane & 15;
  const int g    = lane >> 4;
  const int n     = blockIdx.x >> 6;
  const int panel = blockIdx.x & 63;
  const int m0    = panel * 32;
  const int tile = wave >> 1;    // compute role: 2 tiles x 2 k-halves
  const int kh   = wave & 1;

  const size_t pb = ((size_t)n * Mdim + m0) * Mdim;
  const unsigned short* Ap = xswz + ((size_t)n * NSTEP) * 512 + lane * 8;

  f32x4 acc = {0.f, 0.f, 0.f, 0.f};

  for (int c = 0; c < Mdim / 256; ++c) {     // 8 chunks of 256 cols
    if (c) __syncthreads();                  // protect cvt overwrite
    #pragma unroll
    for (int it = 0; it < 8; ++it) {
      const int u = it * 256 + tid;          // 2048 units = 32 rows x 64 f32x4
      const int r = u >> 6, c4 = (u & 63) * 4;
      f32x4 v = ldnt4(Lf + pb + (size_t)r * Mdim + c * 256 + c4);
      ushort4 bb;
      bb.x = f2b(v.x); bb.y = f2b(v.y); bb.z = f2b(v.z); bb.w = f2b(v.w);
      *reinterpret_cast<ushort4*>(&sm.cvt[r][c4]) = bb;
    }
    __syncthreads();

    // emit 16 fragments (all waves; contiguous 1KB stores)
    #pragma unroll
    for (int q = 0; q < 4; ++q) {
      const int fid = wave * 4 + q;
      const int ct = fid >> 3, sl = fid & 7;
      bf16x8 frag = *reinterpret_cast<const bf16x8*>(
          &sm.cvt[ct * 16 + lr][sl * 32 + g * 8]);
      *reinterpret_cast<bf16x8*>(
          Lb + (((size_t)n * NRT + panel * 2 + ct) * NSTEP + c * 8 + sl) * 512
             + lane * 8) = frag;
    }

    // pass-1 MFMA on the staged chunk (waves whose k-half covers it)
    if ((c >> 2) == kh) {
      #pragma unroll
      for (int sl = 0; sl < 8; ++sl) {
        const int s = c * 8 + sl;
        bf16x8 a = *reinterpret_cast<const bf16x8*>(Ap + (size_t)s * 512);
        bf16x8 b = *reinterpret_cast<const bf16x8*>(
            &sm.cvt[tile * 16 + lr][sl * 32 + g * 8]);
        acc = __builtin_amdgcn_mfma_f32_16x16x32_bf16(a, b, acc, 0, 0, 0);
      }
    }
  }

  // combine the two k-halves; write T1 linear + T1 fragments
  __syncthreads();
  if (kh == 1) sm.part[tile][lane] = acc;
  __syncthreads();
  if (kh == 0) {
    const f32x4 o = sm.part[tile][lane];
    // D layout (m89-verified): col = lane&15, row = (lane>>4)*4 + r (= f)
    #pragma unroll
    for (int r = 0; r < 4; ++r) {
      const int f = g * 4 + r;
      const size_t oi = ((size_t)n * FINC + f) * Mdim + (panel * 2 + tile) * 16 + lr;
      const float v = acc[r] + o[r];
      T1f[oi] = v;
      sm.Tt[tile * 16 + lr][f] = v;
    }
  }
  __syncthreads();
  if (wave == 0) {
    bf16x8 frag;
    #pragma unroll
    for (int j = 0; j < 8; ++j)
      frag[j] = (short)f2b(sm.Tt[g * 8 + j][lr]);
    *reinterpret_cast<bf16x8*>(
        T1swz + ((size_t)n * NSTEP + panel) * 512 + lane * 8) = frag;
  }
}

// One Chebyshev pass via MFMA; all hot-loop loads coalesced (round-5 proven).
// MODE 0: B from LbSwz (bf16 fragment layout). MODE 2: gather f32 L (fallback).
template<int MODE, bool FIRST, bool WRITEA>
__global__ __launch_bounds__(256, 4)
void cheb_mfma(const float* __restrict__ Lf,
               const unsigned short* __restrict__ LbSwz_r,
               const unsigned short* __restrict__ Aswz,
               const float* __restrict__ P2t,
               float* __restrict__ Tf,
               unsigned short* __restrict__ Aswz_next) {
  constexpr int UNR = (MODE == 0) ? 8 : 4;
  const int tid  = threadIdx.x;
  const int wave = tid >> 6;
  const int lane = tid & 63;
  const int tile = wave >> 1;          // 2 tiles per block
  const int kh   = wave & 1;           // k-half
  const int n    = blockIdx.x >> 6;
  const int panel = blockIdx.x & 63;
  const int rt   = panel * 2 + tile;
  const int row0 = rt * 16;
  const int lr   = lane & 15;
  const int g    = lane >> 4;

  const unsigned short* Ap = Aswz + ((size_t)n * NSTEP + kh * 32) * 512 + lane * 8;
  const size_t Bfrag = (((size_t)n * NRT + rt) * NSTEP + kh * 32) * 512 + lane * 8;
  const size_t Lrow  = ((size_t)n * Mdim + row0 + lr) * Mdim;

  f32x4 acc = {0.f, 0.f, 0.f, 0.f};

  for (int jj = 0; jj < 32; jj += UNR) {
    #pragma unroll
    for (int uu = 0; uu < UNR; ++uu) {
      const int sl = jj + uu;
      bf16x8 a = *reinterpret_cast<const bf16x8*>(Ap + (size_t)sl * 512);
      bf16x8 b;
      if (MODE == 0) {
        b = *reinterpret_cast<const bf16x8*>(LbSwz_r + Bfrag + (size_t)sl * 512);
      } else {
        const int ka = (kh * 32 + sl) * 32 + g * 8;
        f32x4 lo = ldnt4(Lf + Lrow + ka);
        f32x4 hi = ldnt4(Lf + Lrow + ka + 4);
        b[0] = (short)f2b(lo.x); b[1] = (short)f2b(lo.y);
        b[2] = (short)f2b(lo.z); b[3] = (short)f2b(lo.w);
        b[4] = (short)f2b(hi.x); b[5] = (short)f2b(hi.y);
        b[6] = (short)f2b(hi.z); b[7] = (short)f2b(hi.w);
      }
      acc = __builtin_amdgcn_mfma_f32_16x16x32_bf16(a, b, acc, 0, 0, 0);
    }
  }

  __shared__ f32x4 part[2][64];
  __shared__ float Tt[32][17];
  if (kh == 1) part[tile][lane] = acc;
  __syncthreads();
  if (kh == 0) {
    const f32x4 o = part[tile][lane];
    #pragma unroll
    for (int r = 0; r < 4; ++r) {
      const int f = g * 4 + r;
      const size_t oi = ((size_t)n * FINC + f) * Mdim + row0 + lr;
      float v = acc[r] + o[r];
      if constexpr (!FIRST) v = 2.f * v - P2t[oi];
      Tf[oi] = v;
      if (WRITEA) Tt[tile * 16 + lr][f] = v;
    }
  }
  if constexpr (WRITEA) {
    __syncthreads();
    if (wave == 0) {
      bf16x8 frag;
      #pragma unroll
      for (int j = 0; j < 8; ++j)
        frag[j] = (short)f2b(Tt[(lane >> 4) * 8 + j][lane & 15]);
      *reinterpret_cast<bf16x8*>(
          Aswz_next + ((size_t)n * NSTEP + panel) * 512 + lane * 8) = frag;
    }
  }
}

// Epilogue: out = relu(feat @ W + B); feat[n*m][f*6+kk] = T_kk^T[n][f][m]
constexpr int EROWS = 32;
struct EpiSmem {
  float W[KORD * FINC][FOUTC];
  float feat[EROWS][KORD * FINC + 1];
  float B[FOUTC];
};

__global__ __launch_bounds__(256)
void epilogue_kernel(const float* __restrict__ xt,
                     const float* __restrict__ Tws,
                     const float* __restrict__ Wg,
                     const float* __restrict__ Bg,
                     float* __restrict__ out) {
  __shared__ EpiSmem sm;
  const int tid = threadIdx.x;
  const int n       = blockIdx.x >> 6;
  const int rowbase = (blockIdx.x & 63) * EROWS;

  for (int u = tid; u < (KORD * FINC * FOUTC) / 4; u += 256) {
    const int fi = u >> 5, fo4 = u & 31;
    *reinterpret_cast<float4*>(&sm.W[fi][fo4 * 4]) =
        *reinterpret_cast<const float4*>(&Wg[fi * FOUTC + fo4 * 4]);
  }
  if (tid < FOUTC / 4)
    *reinterpret_cast<float4*>(&sm.B[tid * 4]) =
        *reinterpret_cast<const float4*>(&Bg[tid * 4]);
  #pragma unroll
  for (int kk = 0; kk < KORD; ++kk) {
    const float* src = (kk == 0) ? xt : (Tws + (size_t)(kk - 1) * TSZ);
    for (int u = tid; u < EROWS * FINC; u += 256) {
      const int r = u & 31, f = u >> 5;
      sm.feat[r][f * KORD + kk] =
          src[((size_t)n * FINC + f) * Mdim + rowbase + r];
    }
  }
  __syncthreads();

  const int row = tid & 31;
  const int fo8 = tid >> 5;
  float acc[16];
  #pragma unroll
  for (int q = 0; q < 16; ++q) acc[q] = sm.B[fo8 * 16 + q];

  #pragma unroll 4
  for (int fi = 0; fi < KORD * FINC; ++fi) {
    const float fv = sm.feat[row][fi];
    #pragma unroll
    for (int q = 0; q < 4; ++q) {
      float4 wv = *reinterpret_cast<const float4*>(&sm.W[fi][fo8 * 16 + q * 4]);
      acc[q * 4]     = fmaf(fv, wv.x, acc[q * 4]);
      acc[q * 4 + 1] = fmaf(fv, wv.y, acc[q * 4 + 1]);
      acc[q * 4 + 2] = fmaf(fv, wv.z, acc[q * 4 + 2]);
      acc[q * 4 + 3] = fmaf(fv, wv.w, acc[q * 4 + 3]);
    }
  }

  const size_t obase = ((size_t)n * Mdim + rowbase + row) * FOUTC + fo8 * 16;
  #pragma unroll
  for (int q = 0; q < 4; ++q) {
    float4 ov;
    ov.x = fmaxf(acc[q * 4], 0.f);
    ov.y = fmaxf(acc[q * 4 + 1], 0.f);
    ov.z = fmaxf(acc[q * 4 + 2], 0.f);
    ov.w = fmaxf(acc[q * 4 + 3], 0.f);
    *reinterpret_cast<float4*>(&out[obase + q * 4]) = ov;
  }
}

extern "C" void kernel_launch(void* const* d_in, const int* in_sizes, int n_in,
                              void* d_out, int out_size, void* d_ws, size_t ws_size,
                              hipStream_t stream) {
  const float* x = (const float*)d_in[0];
  const float* L = (const float*)d_in[1];
  const float* W = (const float*)d_in[2];
  const float* B = (const float*)d_in[3];
  float* out = (float*)d_out;

  constexpr size_t LB_ELEMS = (size_t)Nb * Mdim * Mdim;
  const size_t need_full = LB_ELEMS * 2 + TSZ * 4 * 6 + TSZ * 2 * 6;  // ~152 MB
  const bool lb = ws_size >= need_full;

  char* p = (char*)d_ws;
  unsigned short* Lbuf = (unsigned short*)p;   // fragment-order bf16 L
  if (lb) p += LB_ELEMS * 2;
  float* xt_f = (float*)p;            p += TSZ * 4;
  float* T1f  = (float*)p;            p += TSZ * 4 * 5;
  unsigned short* xswz = (unsigned short*)p;  p += TSZ * 2;
  unsigned short* Tswz = (unsigned short*)p;

  float*          Tf[5] = {T1f, T1f + TSZ, T1f + 2 * TSZ, T1f + 3 * TSZ, T1f + 4 * TSZ};
  unsigned short* Ts[5] = {Tswz, Tswz + TSZ, Tswz + 2 * TSZ, Tswz + 3 * TSZ, Tswz + 4 * TSZ};

  dim3 blk(256);
  hipLaunchKernelGGL(prep_lin, dim3(Nb * FINC), blk, 0, stream, x, xt_f);
  hipLaunchKernelGGL(prep_swz, dim3(Nb), blk, 0, stream, x, xswz);

  dim3 grid(Nb * 64);   // 1024 blocks
  if (lb) {
    hipLaunchKernelGGL(conv_pass1, grid, blk, 0, stream,
                       L, Lbuf, xswz, Tf[0], Ts[0]);
    hipLaunchKernelGGL((cheb_mfma<0, false, true>), grid, blk, 0, stream,
                       nullptr, Lbuf, Ts[0], xt_f, Tf[1], Ts[1]);
    hipLaunchKernelGGL((cheb_mfma<0, false, true>), grid, blk, 0, stream,
                       nullptr, Lbuf, Ts[1], Tf[0], Tf[2], Ts[2]);
    hipLaunchKernelGGL((cheb_mfma<0, false, true>), grid, blk, 0, stream,
                       nullptr, Lbuf, Ts[2], Tf[1], Tf[3], Ts[3]);
    hipLaunchKernelGGL((cheb_mfma<0, false, false>), grid, blk, 0, stream,
                       nullptr, Lbuf, Ts[3], Tf[2], Tf[4], nullptr);
  } else {
    hipLaunchKernelGGL((cheb_mfma<2, true, true>), grid, blk, 0, stream,
                       L, nullptr, xswz, nullptr, Tf[0], Ts[0]);
    hipLaunchKernelGGL((cheb_mfma<2, false, true>), grid, blk, 0, stream,
                       L, nullptr, Ts[0], xt_f, Tf[1], Ts[1]);
    hipLaunchKernelGGL((cheb_mfma<2, false, true>), grid, blk, 0, stream,
                       L, nullptr, Ts[1], Tf[0], Tf[2], Ts[2]);
    hipLaunchKernelGGL((cheb_mfma<2, false, true>), grid, blk, 0, stream,
                       L, nullptr, Ts[2], Tf[1], Tf[3], Ts[3]);
    hipLaunchKernelGGL((cheb_mfma<2, false, false>), grid, blk, 0, stream,
                       L, nullptr, Ts[3], Tf[2], Tf[4], nullptr);
  }

  hipLaunchKernelGGL(epilogue_kernel, dim3(Nb * (Mdim / EROWS)), blk, 0, stream,
                     xt_f, T1f, W, B, out);
}

// Round 8
// 207.450 us; speedup vs baseline: 1.3279x; 1.0845x over previous
//
#include <hip/hip_runtime.h>
#include <hip/hip_bf16.h>

constexpr int Nb    = 16;
constexpr int Mdim  = 2048;
constexpr int FINC  = 16;
constexpr int KORD  = 6;
constexpr int FOUTC = 128;
constexpr int NSTEP = Mdim / 32;   // 64 k-steps
constexpr int NRT   = Mdim / 16;   // 128 row tiles
constexpr size_t TSZ = (size_t)Nb * Mdim * FINC;

typedef __attribute__((ext_vector_type(8))) short bf16x8;
typedef __attribute__((ext_vector_type(4))) float f32x4;

__device__ __forceinline__ unsigned short f2b(float f) {
  unsigned int u = __float_as_uint(f);
  u += 0x7FFFu + ((u >> 16) & 1u);      // round-to-nearest-even
  return (unsigned short)(u >> 16);
}
__device__ __forceinline__ f32x4 ldnt4(const float* p) {
  return __builtin_nontemporal_load(reinterpret_cast<const f32x4*>(p));
}

// Fused prep: sub<16 -> xt_f[n][f][m] = x[n][m][f]; sub==16 -> xswz fragments.
// fragment(s, lane, j) = x^T[f = lane&15][m = s*32 + (lane>>4)*8 + j]
__global__ __launch_bounds__(256)
void prep_both(const float* __restrict__ x,
               float* __restrict__ xt_f,
               unsigned short* __restrict__ xswz) {
  const int n = blockIdx.x / 17, sub = blockIdx.x % 17;
  if (sub < 16) {
    const int f = sub;
    for (int m = threadIdx.x; m < Mdim; m += 256)
      xt_f[((size_t)n * FINC + f) * Mdim + m] = x[((size_t)n * Mdim + m) * FINC + f];
  } else {
    const int lane = threadIdx.x & 63, w4 = threadIdx.x >> 6;
    for (int s = w4; s < NSTEP; s += 4) {
      const int mb = s * 32 + (lane >> 4) * 8;
      const int f  = lane & 15;
      bf16x8 frag;
      #pragma unroll
      for (int j = 0; j < 8; ++j)
        frag[j] = (short)f2b(x[((size_t)n * Mdim + mb + j) * FINC + f]);
      *reinterpret_cast<bf16x8*>(xswz + ((size_t)n * NSTEP + s) * 512 + lane * 8) = frag;
    }
  }
}

struct ConvSmem {
  unsigned short cvt[32][264];   // 16896 B: 32-row x 256-col bf16 chunk (padded)
  f32x4 part[2][64];             // 4096 B : k-half combine
  float Tt[32][17];              // 2176 B : T1 tile transpose
};

// Convert this block's 32-row L panel to fragment-order bf16 Lb AND compute
// pass 1 (T1 = L x). T14 async-split: chunk c+1's global loads are issued
// before chunk c's processing (frag stores + MFMA); LDS write after barrier.
__global__ __launch_bounds__(256, 3)
void conv_pass1(const float* __restrict__ Lf,
                unsigned short* __restrict__ Lb,
                const unsigned short* __restrict__ xswz,
                float* __restrict__ T1f,
                unsigned short* __restrict__ T1swz) {
  __shared__ ConvSmem sm;
  const int tid  = threadIdx.x;
  const int wave = tid >> 6;
  const int lane = tid & 63;
  const int lr   = lane & 15;
  const int g    = lane >> 4;
  const int n     = blockIdx.x >> 6;
  const int panel = blockIdx.x & 63;
  const int m0    = panel * 32;
  const int tile = wave >> 1;    // compute role: 2 tiles x 2 k-halves
  const int kh   = wave & 1;

  const size_t pb = ((size_t)n * Mdim + m0) * Mdim;
  const unsigned short* Ap = xswz + ((size_t)n * NSTEP) * 512 + lane * 8;
  const int rr = tid >> 3;              // load mapping: 2048 units/chunk
  const int cc4 = (tid & 7) * 4;        // rr = u>>6 with u=it*256+tid... see below

  f32x4 acc = {0.f, 0.f, 0.f, 0.f};
  f32x4 rg[8];

  // issue loads for chunk 0
  #pragma unroll
  for (int it = 0; it < 8; ++it) {
    const int u = it * 256 + tid;
    const int r = u >> 6, c4 = (u & 63) * 4;
    rg[it] = ldnt4(Lf + pb + (size_t)r * Mdim + c4);
  }

  for (int c = 0; c < Mdim / 256; ++c) {     // 8 chunks of 256 cols
    if (c) __syncthreads();                  // prev processing done
    // convert staged registers -> LDS
    #pragma unroll
    for (int it = 0; it < 8; ++it) {
      const int u = it * 256 + tid;
      const int r = u >> 6, c4 = (u & 63) * 4;
      ushort4 bb;
      bb.x = f2b(rg[it].x); bb.y = f2b(rg[it].y);
      bb.z = f2b(rg[it].z); bb.w = f2b(rg[it].w);
      *reinterpret_cast<ushort4*>(&sm.cvt[r][c4]) = bb;
    }
    __syncthreads();
    // issue next chunk's loads (overlap with processing below)
    if (c + 1 < Mdim / 256) {
      #pragma unroll
      for (int it = 0; it < 8; ++it) {
        const int u = it * 256 + tid;
        const int r = u >> 6, c4 = (u & 63) * 4;
        rg[it] = ldnt4(Lf + pb + (size_t)r * Mdim + (c + 1) * 256 + c4);
      }
    }

    // emit 16 fragments (all waves; contiguous 1KB stores)
    #pragma unroll
    for (int q = 0; q < 4; ++q) {
      const int fid = wave * 4 + q;
      const int ct = fid >> 3, sl = fid & 7;
      bf16x8 frag = *reinterpret_cast<const bf16x8*>(
          &sm.cvt[ct * 16 + lr][sl * 32 + g * 8]);
      *reinterpret_cast<bf16x8*>(
          Lb + (((size_t)n * NRT + panel * 2 + ct) * NSTEP + c * 8 + sl) * 512
             + lane * 8) = frag;
    }

    // pass-1 MFMA on the staged chunk (waves whose k-half covers it)
    if ((c >> 2) == kh) {
      #pragma unroll
      for (int sl = 0; sl < 8; ++sl) {
        const int s = c * 8 + sl;
        bf16x8 a = *reinterpret_cast<const bf16x8*>(Ap + (size_t)s * 512);
        bf16x8 b = *reinterpret_cast<const bf16x8*>(
            &sm.cvt[tile * 16 + lr][sl * 32 + g * 8]);
        acc = __builtin_amdgcn_mfma_f32_16x16x32_bf16(a, b, acc, 0, 0, 0);
      }
    }
  }

  // combine the two k-halves; write T1 linear + T1 fragments
  __syncthreads();
  if (kh == 1) sm.part[tile][lane] = acc;
  __syncthreads();
  if (kh == 0) {
    const f32x4 o = sm.part[tile][lane];
    // D layout (m89-verified): col = lane&15, row = (lane>>4)*4 + r (= f)
    #pragma unroll
    for (int r = 0; r < 4; ++r) {
      const int f = g * 4 + r;
      const size_t oi = ((size_t)n * FINC + f) * Mdim + (panel * 2 + tile) * 16 + lr;
      const float v = acc[r] + o[r];
      T1f[oi] = v;
      sm.Tt[tile * 16 + lr][f] = v;
    }
  }
  __syncthreads();
  if (wave == 0) {
    bf16x8 frag;
    #pragma unroll
    for (int j = 0; j < 8; ++j)
      frag[j] = (short)f2b(sm.Tt[g * 8 + j][lr]);
    *reinterpret_cast<bf16x8*>(
        T1swz + ((size_t)n * NSTEP + panel) * 512 + lane * 8) = frag;
  }
}

// Middle Chebyshev pass (2..4) via MFMA; all hot-loop loads coalesced.
// MODE 0: B from LbSwz (bf16 fragment layout). MODE 2: gather f32 L (fallback).
template<int MODE, bool FIRST, bool WRITEA>
__global__ __launch_bounds__(256, 4)
void cheb_mfma(const float* __restrict__ Lf,
               const unsigned short* __restrict__ LbSwz_r,
               const unsigned short* __restrict__ Aswz,
               const float* __restrict__ P2t,
               float* __restrict__ Tf,
               unsigned short* __restrict__ Aswz_next) {
  constexpr int UNR = (MODE == 0) ? 8 : 4;
  const int tid  = threadIdx.x;
  const int wave = tid >> 6;
  const int lane = tid & 63;
  const int tile = wave >> 1;
  const int kh   = wave & 1;
  const int n    = blockIdx.x >> 6;
  const int panel = blockIdx.x & 63;
  const int rt   = panel * 2 + tile;
  const int row0 = rt * 16;
  const int lr   = lane & 15;
  const int g    = lane >> 4;

  const unsigned short* Ap = Aswz + ((size_t)n * NSTEP + kh * 32) * 512 + lane * 8;
  const size_t Bfrag = (((size_t)n * NRT + rt) * NSTEP + kh * 32) * 512 + lane * 8;
  const size_t Lrow  = ((size_t)n * Mdim + row0 + lr) * Mdim;

  f32x4 acc = {0.f, 0.f, 0.f, 0.f};

  for (int jj = 0; jj < 32; jj += UNR) {
    #pragma unroll
    for (int uu = 0; uu < UNR; ++uu) {
      const int sl = jj + uu;
      bf16x8 a = *reinterpret_cast<const bf16x8*>(Ap + (size_t)sl * 512);
      bf16x8 b;
      if (MODE == 0) {
        b = *reinterpret_cast<const bf16x8*>(LbSwz_r + Bfrag + (size_t)sl * 512);
      } else {
        const int ka = (kh * 32 + sl) * 32 + g * 8;
        f32x4 lo = ldnt4(Lf + Lrow + ka);
        f32x4 hi = ldnt4(Lf + Lrow + ka + 4);
        b[0] = (short)f2b(lo.x); b[1] = (short)f2b(lo.y);
        b[2] = (short)f2b(lo.z); b[3] = (short)f2b(lo.w);
        b[4] = (short)f2b(hi.x); b[5] = (short)f2b(hi.y);
        b[6] = (short)f2b(hi.z); b[7] = (short)f2b(hi.w);
      }
      acc = __builtin_amdgcn_mfma_f32_16x16x32_bf16(a, b, acc, 0, 0, 0);
    }
  }

  __shared__ f32x4 part[2][64];
  __shared__ float Tt[32][17];
  if (kh == 1) part[tile][lane] = acc;
  __syncthreads();
  if (kh == 0) {
    const f32x4 o = part[tile][lane];
    #pragma unroll
    for (int r = 0; r < 4; ++r) {
      const int f = g * 4 + r;
      const size_t oi = ((size_t)n * FINC + f) * Mdim + row0 + lr;
      float v = acc[r] + o[r];
      if constexpr (!FIRST) v = 2.f * v - P2t[oi];
      Tf[oi] = v;
      if (WRITEA) Tt[tile * 16 + lr][f] = v;
    }
  }
  if constexpr (WRITEA) {
    __syncthreads();
    if (wave == 0) {
      bf16x8 frag;
      #pragma unroll
      for (int j = 0; j < 8; ++j)
        frag[j] = (short)f2b(Tt[(lane >> 4) * 8 + j][lane & 15]);
      *reinterpret_cast<bf16x8*>(
          Aswz_next + ((size_t)n * NSTEP + panel) * 512 + lane * 8) = frag;
    }
  }
}

// Pass 5 fused with the epilogue: block computes T5 for its 32 rows, drops it
// straight into the feat tile, and finishes out = relu(feat @ W + B).
struct P5Smem {
  float W[KORD * FINC][FOUTC];          // 49152 B
  float feat[32][KORD * FINC + 1];      // 12416 B
  float Bv[FOUTC];                      // 512 B
  f32x4 part[2][64];                    // 4096 B
};

__global__ __launch_bounds__(256, 2)
void pass5_epi(const unsigned short* __restrict__ LbSwz,
               const unsigned short* __restrict__ Aswz,   // T4 fragments
               const float* __restrict__ P2t,             // T3 linear
               const float* __restrict__ xt,              // x^T linear
               const float* __restrict__ Tws,             // T1..T4 linear
               const float* __restrict__ Wg,
               const float* __restrict__ Bg,
               float* __restrict__ out) {
  __shared__ P5Smem sm;
  const int tid  = threadIdx.x;
  const int wave = tid >> 6;
  const int lane = tid & 63;
  const int tile = wave >> 1;
  const int kh   = wave & 1;
  const int n    = blockIdx.x >> 6;
  const int panel = blockIdx.x & 63;
  const int rt   = panel * 2 + tile;
  const int row0 = rt * 16;
  const int rowbase = panel * 32;
  const int lr   = lane & 15;
  const int g    = lane >> 4;

  // stage W, B, feat slots kk=0..4 (independent of the MFMA work)
  for (int u = tid; u < (KORD * FINC * FOUTC) / 4; u += 256) {
    const int fi = u >> 5, fo4 = u & 31;
    *reinterpret_cast<float4*>(&sm.W[fi][fo4 * 4]) =
        *reinterpret_cast<const float4*>(&Wg[fi * FOUTC + fo4 * 4]);
  }
  if (tid < FOUTC / 4)
    *reinterpret_cast<float4*>(&sm.Bv[tid * 4]) =
        *reinterpret_cast<const float4*>(&Bg[tid * 4]);
  #pragma unroll
  for (int kk = 0; kk < KORD - 1; ++kk) {
    const float* src = (kk == 0) ? xt : (Tws + (size_t)(kk - 1) * TSZ);
    for (int u = tid; u < 32 * FINC; u += 256) {
      const int r = u & 31, f = u >> 5;
      sm.feat[r][f * KORD + kk] =
          src[((size_t)n * FINC + f) * Mdim + rowbase + r];
    }
  }

  // pass-5 MFMA (identical to cheb_mfma MODE 0)
  const unsigned short* Ap = Aswz + ((size_t)n * NSTEP + kh * 32) * 512 + lane * 8;
  const size_t Bfrag = (((size_t)n * NRT + rt) * NSTEP + kh * 32) * 512 + lane * 8;
  f32x4 acc = {0.f, 0.f, 0.f, 0.f};
  for (int jj = 0; jj < 32; jj += 8) {
    #pragma unroll
    for (int uu = 0; uu < 8; ++uu) {
      const int sl = jj + uu;
      bf16x8 a = *reinterpret_cast<const bf16x8*>(Ap + (size_t)sl * 512);
      bf16x8 b = *reinterpret_cast<const bf16x8*>(LbSwz + Bfrag + (size_t)sl * 512);
      acc = __builtin_amdgcn_mfma_f32_16x16x32_bf16(a, b, acc, 0, 0, 0);
    }
  }

  __syncthreads();
  if (kh == 1) sm.part[tile][lane] = acc;
  __syncthreads();
  if (kh == 0) {
    const f32x4 o = sm.part[tile][lane];
    #pragma unroll
    for (int r = 0; r < 4; ++r) {
      const int f = g * 4 + r;
      const size_t oi = ((size_t)n * FINC + f) * Mdim + row0 + lr;
      const float v = 2.f * (acc[r] + o[r]) - P2t[oi];
      sm.feat[tile * 16 + lr][f * KORD + 5] = v;   // T5 -> feat, no global write
    }
  }
  __syncthreads();

  // mini-GEMM epilogue: out[rowbase..+32][0..128)
  const int row = tid & 31;
  const int fo8 = tid >> 5;
  float oacc[16];
  #pragma unroll
  for (int q = 0; q < 16; ++q) oacc[q] = sm.Bv[fo8 * 16 + q];

  #pragma unroll 4
  for (int fi = 0; fi < KORD * FINC; ++fi) {
    const float fv = sm.feat[row][fi];
    #pragma unroll
    for (int q = 0; q < 4; ++q) {
      float4 wv = *reinterpret_cast<const float4*>(&sm.W[fi][fo8 * 16 + q * 4]);
      oacc[q * 4]     = fmaf(fv, wv.x, oacc[q * 4]);
      oacc[q * 4 + 1] = fmaf(fv, wv.y, oacc[q * 4 + 1]);
      oacc[q * 4 + 2] = fmaf(fv, wv.z, oacc[q * 4 + 2]);
      oacc[q * 4 + 3] = fmaf(fv, wv.w, oacc[q * 4 + 3]);
    }
  }

  const size_t obase = ((size_t)n * Mdim + rowbase + row) * FOUTC + fo8 * 16;
  #pragma unroll
  for (int q = 0; q < 4; ++q) {
    float4 ov;
    ov.x = fmaxf(oacc[q * 4], 0.f);
    ov.y = fmaxf(oacc[q * 4 + 1], 0.f);
    ov.z = fmaxf(oacc[q * 4 + 2], 0.f);
    ov.w = fmaxf(oacc[q * 4 + 3], 0.f);
    *reinterpret_cast<float4*>(&out[obase + q * 4]) = ov;
  }
}

// Standalone epilogue (fallback path only)
constexpr int EROWS = 32;
struct EpiSmem {
  float W[KORD * FINC][FOUTC];
  float feat[EROWS][KORD * FINC + 1];
  float B[FOUTC];
};

__global__ __launch_bounds__(256)
void epilogue_kernel(const float* __restrict__ xt,
                     const float* __restrict__ Tws,
                     const float* __restrict__ Wg,
                     const float* __restrict__ Bg,
                     float* __restrict__ out) {
  __shared__ EpiSmem sm;
  const int tid = threadIdx.x;
  const int n       = blockIdx.x >> 6;
  const int rowbase = (blockIdx.x & 63) * EROWS;

  for (int u = tid; u < (KORD * FINC * FOUTC) / 4; u += 256) {
    const int fi = u >> 5, fo4 = u & 31;
    *reinterpret_cast<float4*>(&sm.W[fi][fo4 * 4]) =
        *reinterpret_cast<const float4*>(&Wg[fi * FOUTC + fo4 * 4]);
  }
  if (tid < FOUTC / 4)
    *reinterpret_cast<float4*>(&sm.B[tid * 4]) =
        *reinterpret_cast<const float4*>(&Bg[tid * 4]);
  #pragma unroll
  for (int kk = 0; kk < KORD; ++kk) {
    const float* src = (kk == 0) ? xt : (Tws + (size_t)(kk - 1) * TSZ);
    for (int u = tid; u < EROWS * FINC; u += 256) {
      const int r = u & 31, f = u >> 5;
      sm.feat[r][f * KORD + kk] =
          src[((size_t)n * FINC + f) * Mdim + rowbase + r];
    }
  }
  __syncthreads();

  const int row = tid & 31;
  const int fo8 = tid >> 5;
  float acc[16];
  #pragma unroll
  for (int q = 0; q < 16; ++q) acc[q] = sm.B[fo8 * 16 + q];

  #pragma unroll 4
  for (int fi = 0; fi < KORD * FINC; ++fi) {
    const float fv = sm.feat[row][fi];
    #pragma unroll
    for (int q = 0; q < 4; ++q) {
      float4 wv = *reinterpret_cast<const float4*>(&sm.W[fi][fo8 * 16 + q * 4]);
      acc[q * 4]     = fmaf(fv, wv.x, acc[q * 4]);
      acc[q * 4 + 1] = fmaf(fv, wv.y, acc[q * 4 + 1]);
      acc[q * 4 + 2] = fmaf(fv, wv.z, acc[q * 4 + 2]);
      acc[q * 4 + 3] = fmaf(fv, wv.w, acc[q * 4 + 3]);
    }
  }

  const size_t obase = ((size_t)n * Mdim + rowbase + row) * FOUTC + fo8 * 16;
  #pragma unroll
  for (int q = 0; q < 4; ++q) {
    float4 ov;
    ov.x = fmaxf(acc[q * 4], 0.f);
    ov.y = fmaxf(acc[q * 4 + 1], 0.f);
    ov.z = fmaxf(acc[q * 4 + 2], 0.f);
    ov.w = fmaxf(acc[q * 4 + 3], 0.f);
    *reinterpret_cast<float4*>(&out[obase + q * 4]) = ov;
  }
}

extern "C" void kernel_launch(void* const* d_in, const int* in_sizes, int n_in,
                              void* d_out, int out_size, void* d_ws, size_t ws_size,
                              hipStream_t stream) {
  const float* x = (const float*)d_in[0];
  const float* L = (const float*)d_in[1];
  const float* W = (const float*)d_in[2];
  const float* B = (const float*)d_in[3];
  float* out = (float*)d_out;

  constexpr size_t LB_ELEMS = (size_t)Nb * Mdim * Mdim;
  const size_t need_full = LB_ELEMS * 2 + TSZ * 4 * 6 + TSZ * 2 * 6;  // ~152 MB
  const bool lb = ws_size >= need_full;

  char* p = (char*)d_ws;
  unsigned short* Lbuf = (unsigned short*)p;   // fragment-order bf16 L
  if (lb) p += LB_ELEMS * 2;
  float* xt_f = (float*)p;            p += TSZ * 4;
  float* T1f  = (float*)p;            p += TSZ * 4 * 5;
  unsigned short* xswz = (unsigned short*)p;  p += TSZ * 2;
  unsigned short* Tswz = (unsigned short*)p;

  float*          Tf[5] = {T1f, T1f + TSZ, T1f + 2 * TSZ, T1f + 3 * TSZ, T1f + 4 * TSZ};
  unsigned short* Ts[5] = {Tswz, Tswz + TSZ, Tswz + 2 * TSZ, Tswz + 3 * TSZ, Tswz + 4 * TSZ};

  dim3 blk(256);
  hipLaunchKernelGGL(prep_both, dim3(Nb * 17), blk, 0, stream, x, xt_f, xswz);

  dim3 grid(Nb * 64);   // 1024 blocks
  if (lb) {
    hipLaunchKernelGGL(conv_pass1, grid, blk, 0, stream,
                       L, Lbuf, xswz, Tf[0], Ts[0]);
    hipLaunchKernelGGL((cheb_mfma<0, false, true>), grid, blk, 0, stream,
                       nullptr, Lbuf, Ts[0], xt_f, Tf[1], Ts[1]);
    hipLaunchKernelGGL((cheb_mfma<0, false, true>), grid, blk, 0, stream,
                       nullptr, Lbuf, Ts[1], Tf[0], Tf[2], Ts[2]);
    hipLaunchKernelGGL((cheb_mfma<0, false, true>), grid, blk, 0, stream,
                       nullptr, Lbuf, Ts[2], Tf[1], Tf[3], Ts[3]);
    hipLaunchKernelGGL(pass5_epi, grid, blk, 0, stream,
                       Lbuf, Ts[3], Tf[2], xt_f, T1f, W, B, out);
  } else {
    hipLaunchKernelGGL((cheb_mfma<2, true, true>), grid, blk, 0, stream,
                       L, nullptr, xswz, nullptr, Tf[0], Ts[0]);
    hipLaunchKernelGGL((cheb_mfma<2, false, true>), grid, blk, 0, stream,
                       L, nullptr, Ts[0], xt_f, Tf[1], Ts[1]);
    hipLaunchKernelGGL((cheb_mfma<2, false, true>), grid, blk, 0, stream,
                       L, nullptr, Ts[1], Tf[0], Tf[2], Ts[2]);
    hipLaunchKernelGGL((cheb_mfma<2, false, true>), grid, blk, 0, stream,
                       L, nullptr, Ts[2], Tf[1], Tf[3], Ts[3]);
    hipLaunchKernelGGL((cheb_mfma<2, false, false>), grid, blk, 0, stream,
                       L, nullptr, Ts[3], Tf[2], Tf[4], nullptr);
    hipLaunchKernelGGL(epilogue_kernel, dim3(Nb * (Mdim / EROWS)), blk, 0, stream,
                       xt_f, T1f, W, B, out);
  }
}

// Round 9
// 206.610 us; speedup vs baseline: 1.3332x; 1.0041x over previous
//
#include <hip/hip_runtime.h>
#include <hip/hip_bf16.h>

constexpr int Nb    = 16;
constexpr int Mdim  = 2048;
constexpr int FINC  = 16;
constexpr int KORD  = 6;
constexpr int FOUTC = 128;
constexpr int NSTEP = Mdim / 32;   // 64 k-steps
constexpr int NRT   = Mdim / 16;   // 128 row tiles
constexpr size_t TSZ = (size_t)Nb * Mdim * FINC;

typedef __attribute__((ext_vector_type(8))) short bf16x8;
typedef __attribute__((ext_vector_type(4))) float f32x4;

__device__ __forceinline__ unsigned short f2b(float f) {
  unsigned int u = __float_as_uint(f);
  u += 0x7FFFu + ((u >> 16) & 1u);      // round-to-nearest-even
  return (unsigned short)(u >> 16);
}
__device__ __forceinline__ f32x4 ldnt4(const float* p) {
  return __builtin_nontemporal_load(reinterpret_cast<const f32x4*>(p));
}

// Fused prep: sub<16 -> xt_f[n][f][m] = x[n][m][f]; sub==16 -> xswz fragments.
// fragment(s, lane, j) = x^T[f = lane&15][m = s*32 + (lane>>4)*8 + j]
__global__ __launch_bounds__(256)
void prep_both(const float* __restrict__ x,
               float* __restrict__ xt_f,
               unsigned short* __restrict__ xswz) {
  const int n = blockIdx.x / 17, sub = blockIdx.x % 17;
  if (sub < 16) {
    const int f = sub;
    for (int m = threadIdx.x; m < Mdim; m += 256)
      xt_f[((size_t)n * FINC + f) * Mdim + m] = x[((size_t)n * Mdim + m) * FINC + f];
  } else {
    const int lane = threadIdx.x & 63, w4 = threadIdx.x >> 6;
    for (int s = w4; s < NSTEP; s += 4) {
      const int mb = s * 32 + (lane >> 4) * 8;
      const int f  = lane & 15;
      bf16x8 frag;
      #pragma unroll
      for (int j = 0; j < 8; ++j)
        frag[j] = (short)f2b(x[((size_t)n * Mdim + mb + j) * FINC + f]);
      *reinterpret_cast<bf16x8*>(xswz + ((size_t)n * NSTEP + s) * 512 + lane * 8) = frag;
    }
  }
}

struct ConvSmem {
  unsigned short cvt[32][264];   // 16896 B: 32-row x 256-col bf16 chunk (padded)
  f32x4 part[2][64];             // 4096 B : k-half combine
  float Tt[32][17];              // 2176 B : T1 tile transpose
};

// Convert L panels to fragment-order bf16 Lb AND compute pass 1 (T1 = L x).
// 512 blocks x 2 panels each: uniform residency (2/CU), no dispatch tail.
// T14 async-split: next chunk's global loads issued before current chunk's
// processing (frag stores + MFMA).
__global__ __launch_bounds__(256, 3)
void conv_pass1(const float* __restrict__ Lf,
                unsigned short* __restrict__ Lb,
                const unsigned short* __restrict__ xswz,
                float* __restrict__ T1f,
                unsigned short* __restrict__ T1swz) {
  __shared__ ConvSmem sm;
  const int tid  = threadIdx.x;
  const int wave = tid >> 6;
  const int lane = tid & 63;
  const int lr   = lane & 15;
  const int g    = lane >> 4;
  const int n    = blockIdx.x >> 5;
  const int pgrp = blockIdx.x & 31;
  const int tile = wave >> 1;    // compute role: 2 tiles x 2 k-halves
  const int kh   = wave & 1;

  const unsigned short* Ap = xswz + ((size_t)n * NSTEP) * 512 + lane * 8;

  for (int pa = 0; pa < 2; ++pa) {
    const int panel = pgrp * 2 + pa;
    const int m0    = panel * 32;
    const size_t pb = ((size_t)n * Mdim + m0) * Mdim;

    f32x4 acc = {0.f, 0.f, 0.f, 0.f};
    f32x4 rg[8];

    // issue loads for chunk 0 of this panel
    #pragma unroll
    for (int it = 0; it < 8; ++it) {
      const int u = it * 256 + tid;
      const int r = u >> 6, c4 = (u & 63) * 4;
      rg[it] = ldnt4(Lf + pb + (size_t)r * Mdim + c4);
    }

    for (int c = 0; c < Mdim / 256; ++c) {   // 8 chunks of 256 cols
      if (c || pa) __syncthreads();          // prev processing / prev panel done
      // convert staged registers -> LDS
      #pragma unroll
      for (int it = 0; it < 8; ++it) {
        const int u = it * 256 + tid;
        const int r = u >> 6, c4 = (u & 63) * 4;
        ushort4 bb;
        bb.x = f2b(rg[it].x); bb.y = f2b(rg[it].y);
        bb.z = f2b(rg[it].z); bb.w = f2b(rg[it].w);
        *reinterpret_cast<ushort4*>(&sm.cvt[r][c4]) = bb;
      }
      __syncthreads();
      // issue next chunk's loads (overlap with processing below)
      if (c + 1 < Mdim / 256) {
        #pragma unroll
        for (int it = 0; it < 8; ++it) {
          const int u = it * 256 + tid;
          const int r = u >> 6, c4 = (u & 63) * 4;
          rg[it] = ldnt4(Lf + pb + (size_t)r * Mdim + (c + 1) * 256 + c4);
        }
      }

      // emit 16 fragments (all waves; contiguous 1KB stores)
      #pragma unroll
      for (int q = 0; q < 4; ++q) {
        const int fid = wave * 4 + q;
        const int ct = fid >> 3, sl = fid & 7;
        bf16x8 frag = *reinterpret_cast<const bf16x8*>(
            &sm.cvt[ct * 16 + lr][sl * 32 + g * 8]);
        *reinterpret_cast<bf16x8*>(
            Lb + (((size_t)n * NRT + panel * 2 + ct) * NSTEP + c * 8 + sl) * 512
               + lane * 8) = frag;
      }

      // pass-1 MFMA on the staged chunk (waves whose k-half covers it)
      if ((c >> 2) == kh) {
        #pragma unroll
        for (int sl = 0; sl < 8; ++sl) {
          const int s = c * 8 + sl;
          bf16x8 a = *reinterpret_cast<const bf16x8*>(Ap + (size_t)s * 512);
          bf16x8 b = *reinterpret_cast<const bf16x8*>(
              &sm.cvt[tile * 16 + lr][sl * 32 + g * 8]);
          acc = __builtin_amdgcn_mfma_f32_16x16x32_bf16(a, b, acc, 0, 0, 0);
        }
      }
    }

    // combine the two k-halves; write T1 linear + T1 fragments
    __syncthreads();
    if (kh == 1) sm.part[tile][lane] = acc;
    __syncthreads();
    if (kh == 0) {
      const f32x4 o = sm.part[tile][lane];
      // D layout (m89-verified): col = lane&15, row = (lane>>4)*4 + r (= f)
      #pragma unroll
      for (int r = 0; r < 4; ++r) {
        const int f = g * 4 + r;
        const size_t oi = ((size_t)n * FINC + f) * Mdim + (panel * 2 + tile) * 16 + lr;
        const float v = acc[r] + o[r];
        T1f[oi] = v;
        sm.Tt[tile * 16 + lr][f] = v;
      }
    }
    __syncthreads();
    if (wave == 0) {
      bf16x8 frag;
      #pragma unroll
      for (int j = 0; j < 8; ++j)
        frag[j] = (short)f2b(sm.Tt[g * 8 + j][lr]);
      *reinterpret_cast<bf16x8*>(
          T1swz + ((size_t)n * NSTEP + panel) * 512 + lane * 8) = frag;
    }
  }
}

// Middle Chebyshev pass (2..4) via MFMA; all hot-loop loads coalesced.
// MODE 0: B from LbSwz (bf16 fragment layout). MODE 2: gather f32 L (fallback).
template<int MODE, bool FIRST, bool WRITEA>
__global__ __launch_bounds__(256, 4)
void cheb_mfma(const float* __restrict__ Lf,
               const unsigned short* __restrict__ LbSwz_r,
               const unsigned short* __restrict__ Aswz,
               const float* __restrict__ P2t,
               float* __restrict__ Tf,
               unsigned short* __restrict__ Aswz_next) {
  constexpr int UNR = (MODE == 0) ? 8 : 4;
  const int tid  = threadIdx.x;
  const int wave = tid >> 6;
  const int lane = tid & 63;
  const int tile = wave >> 1;
  const int kh   = wave & 1;
  const int n    = blockIdx.x >> 6;
  const int panel = blockIdx.x & 63;
  const int rt   = panel * 2 + tile;
  const int row0 = rt * 16;
  const int lr   = lane & 15;
  const int g    = lane >> 4;

  const unsigned short* Ap = Aswz + ((size_t)n * NSTEP + kh * 32) * 512 + lane * 8;
  const size_t Bfrag = (((size_t)n * NRT + rt) * NSTEP + kh * 32) * 512 + lane * 8;
  const size_t Lrow  = ((size_t)n * Mdim + row0 + lr) * Mdim;

  f32x4 acc = {0.f, 0.f, 0.f, 0.f};

  for (int jj = 0; jj < 32; jj += UNR) {
    #pragma unroll
    for (int uu = 0; uu < UNR; ++uu) {
      const int sl = jj + uu;
      bf16x8 a = *reinterpret_cast<const bf16x8*>(Ap + (size_t)sl * 512);
      bf16x8 b;
      if (MODE == 0) {
        b = *reinterpret_cast<const bf16x8*>(LbSwz_r + Bfrag + (size_t)sl * 512);
      } else {
        const int ka = (kh * 32 + sl) * 32 + g * 8;
        f32x4 lo = ldnt4(Lf + Lrow + ka);
        f32x4 hi = ldnt4(Lf + Lrow + ka + 4);
        b[0] = (short)f2b(lo.x); b[1] = (short)f2b(lo.y);
        b[2] = (short)f2b(lo.z); b[3] = (short)f2b(lo.w);
        b[4] = (short)f2b(hi.x); b[5] = (short)f2b(hi.y);
        b[6] = (short)f2b(hi.z); b[7] = (short)f2b(hi.w);
      }
      acc = __builtin_amdgcn_mfma_f32_16x16x32_bf16(a, b, acc, 0, 0, 0);
    }
  }

  __shared__ f32x4 part[2][64];
  __shared__ float Tt[32][17];
  if (kh == 1) part[tile][lane] = acc;
  __syncthreads();
  if (kh == 0) {
    const f32x4 o = part[tile][lane];
    #pragma unroll
    for (int r = 0; r < 4; ++r) {
      const int f = g * 4 + r;
      const size_t oi = ((size_t)n * FINC + f) * Mdim + row0 + lr;
      float v = acc[r] + o[r];
      if constexpr (!FIRST) v = 2.f * v - P2t[oi];
      Tf[oi] = v;
      if (WRITEA) Tt[tile * 16 + lr][f] = v;
    }
  }
  if constexpr (WRITEA) {
    __syncthreads();
    if (wave == 0) {
      bf16x8 frag;
      #pragma unroll
      for (int j = 0; j < 8; ++j)
        frag[j] = (short)f2b(Tt[(lane >> 4) * 8 + j][lane & 15]);
      *reinterpret_cast<bf16x8*>(
          Aswz_next + ((size_t)n * NSTEP + panel) * 512 + lane * 8) = frag;
    }
  }
}

// Pass 5 fused with the epilogue. 512 blocks x 2 panels: uniform residency
// (2/CU with 66KB LDS), W/B staged ONCE and reused for both panels.
struct P5Smem {
  float W[KORD * FINC][FOUTC];          // 49152 B
  float feat[32][KORD * FINC + 1];      // 12416 B
  float Bv[FOUTC];                      // 512 B
  f32x4 part[2][64];                    // 4096 B
};

__global__ __launch_bounds__(256, 2)
void pass5_epi(const unsigned short* __restrict__ LbSwz,
               const unsigned short* __restrict__ Aswz,   // T4 fragments
               const float* __restrict__ P2t,             // T3 linear
               const float* __restrict__ xt,              // x^T linear
               const float* __restrict__ Tws,             // T1..T4 linear
               const float* __restrict__ Wg,
               const float* __restrict__ Bg,
               float* __restrict__ out) {
  __shared__ P5Smem sm;
  const int tid  = threadIdx.x;
  const int wave = tid >> 6;
  const int lane = tid & 63;
  const int tile = wave >> 1;
  const int kh   = wave & 1;
  const int n    = blockIdx.x >> 5;
  const int pgrp = blockIdx.x & 31;
  const int lr   = lane & 15;
  const int g    = lane >> 4;

  // stage W, B once (reused across both panels)
  for (int u = tid; u < (KORD * FINC * FOUTC) / 4; u += 256) {
    const int fi = u >> 5, fo4 = u & 31;
    *reinterpret_cast<float4*>(&sm.W[fi][fo4 * 4]) =
        *reinterpret_cast<const float4*>(&Wg[fi * FOUTC + fo4 * 4]);
  }
  if (tid < FOUTC / 4)
    *reinterpret_cast<float4*>(&sm.Bv[tid * 4]) =
        *reinterpret_cast<const float4*>(&Bg[tid * 4]);

  const unsigned short* Ap = Aswz + ((size_t)n * NSTEP + kh * 32) * 512 + lane * 8;

  for (int pa = 0; pa < 2; ++pa) {
    const int panel   = pgrp * 2 + pa;
    const int rt      = panel * 2 + tile;
    const int row0    = rt * 16;
    const int rowbase = panel * 32;

    if (pa) __syncthreads();   // prev panel's mini-GEMM feat reads done

    // stage feat slots kk=0..4
    #pragma unroll
    for (int kk = 0; kk < KORD - 1; ++kk) {
      const float* src = (kk == 0) ? xt : (Tws + (size_t)(kk - 1) * TSZ);
      for (int u = tid; u < 32 * FINC; u += 256) {
        const int r = u & 31, f = u >> 5;
        sm.feat[r][f * KORD + kk] =
            src[((size_t)n * FINC + f) * Mdim + rowbase + r];
      }
    }

    // pass-5 MFMA (identical to cheb_mfma MODE 0)
    const size_t Bfrag = (((size_t)n * NRT + rt) * NSTEP + kh * 32) * 512 + lane * 8;
    f32x4 acc = {0.f, 0.f, 0.f, 0.f};
    for (int jj = 0; jj < 32; jj += 8) {
      #pragma unroll
      for (int uu = 0; uu < 8; ++uu) {
        const int sl = jj + uu;
        bf16x8 a = *reinterpret_cast<const bf16x8*>(Ap + (size_t)sl * 512);
        bf16x8 b = *reinterpret_cast<const bf16x8*>(LbSwz + Bfrag + (size_t)sl * 512);
        acc = __builtin_amdgcn_mfma_f32_16x16x32_bf16(a, b, acc, 0, 0, 0);
      }
    }

    __syncthreads();
    if (kh == 1) sm.part[tile][lane] = acc;
    __syncthreads();
    if (kh == 0) {
      const f32x4 o = sm.part[tile][lane];
      #pragma unroll
      for (int r = 0; r < 4; ++r) {
        const int f = g * 4 + r;
        const size_t oi = ((size_t)n * FINC + f) * Mdim + row0 + lr;
        const float v = 2.f * (acc[r] + o[r]) - P2t[oi];
        sm.feat[tile * 16 + lr][f * KORD + 5] = v;   // T5 -> feat, no global write
      }
    }
    __syncthreads();

    // mini-GEMM epilogue: out[rowbase..+32][0..128)
    const int row = tid & 31;
    const int fo8 = tid >> 5;
    float oacc[16];
    #pragma unroll
    for (int q = 0; q < 16; ++q) oacc[q] = sm.Bv[fo8 * 16 + q];

    #pragma unroll 4
    for (int fi = 0; fi < KORD * FINC; ++fi) {
      const float fv = sm.feat[row][fi];
      #pragma unroll
      for (int q = 0; q < 4; ++q) {
        float4 wv = *reinterpret_cast<const float4*>(&sm.W[fi][fo8 * 16 + q * 4]);
        oacc[q * 4]     = fmaf(fv, wv.x, oacc[q * 4]);
        oacc[q * 4 + 1] = fmaf(fv, wv.y, oacc[q * 4 + 1]);
        oacc[q * 4 + 2] = fmaf(fv, wv.z, oacc[q * 4 + 2]);
        oacc[q * 4 + 3] = fmaf(fv, wv.w, oacc[q * 4 + 3]);
      }
    }

    const size_t obase = ((size_t)n * Mdim + rowbase + row) * FOUTC + fo8 * 16;
    #pragma unroll
    for (int q = 0; q < 4; ++q) {
      float4 ov;
      ov.x = fmaxf(oacc[q * 4], 0.f);
      ov.y = fmaxf(oacc[q * 4 + 1], 0.f);
      ov.z = fmaxf(oacc[q * 4 + 2], 0.f);
      ov.w = fmaxf(oacc[q * 4 + 3], 0.f);
      *reinterpret_cast<float4*>(&out[obase + q * 4]) = ov;
    }
  }
}

// Standalone epilogue (fallback path only)
constexpr int EROWS = 32;
struct EpiSmem {
  float W[KORD * FINC][FOUTC];
  float feat[EROWS][KORD * FINC + 1];
  float B[FOUTC];
};

__global__ __launch_bounds__(256)
void epilogue_kernel(const float* __restrict__ xt,
                     const float* __restrict__ Tws,
                     const float* __restrict__ Wg,
                     const float* __restrict__ Bg,
                     float* __restrict__ out) {
  __shared__ EpiSmem sm;
  const int tid = threadIdx.x;
  const int n       = blockIdx.x >> 6;
  const int rowbase = (blockIdx.x & 63) * EROWS;

  for (int u = tid; u < (KORD * FINC * FOUTC) / 4; u += 256) {
    const int fi = u >> 5, fo4 = u & 31;
    *reinterpret_cast<float4*>(&sm.W[fi][fo4 * 4]) =
        *reinterpret_cast<const float4*>(&Wg[fi * FOUTC + fo4 * 4]);
  }
  if (tid < FOUTC / 4)
    *reinterpret_cast<float4*>(&sm.B[tid * 4]) =
        *reinterpret_cast<const float4*>(&Bg[tid * 4]);
  #pragma unroll
  for (int kk = 0; kk < KORD; ++kk) {
    const float* src = (kk == 0) ? xt : (Tws + (size_t)(kk - 1) * TSZ);
    for (int u = tid; u < EROWS * FINC; u += 256) {
      const int r = u & 31, f = u >> 5;
      sm.feat[r][f * KORD + kk] =
          src[((size_t)n * FINC + f) * Mdim + rowbase + r];
    }
  }
  __syncthreads();

  const int row = tid & 31;
  const int fo8 = tid >> 5;
  float acc[16];
  #pragma unroll
  for (int q = 0; q < 16; ++q) acc[q] = sm.B[fo8 * 16 + q];

  #pragma unroll 4
  for (int fi = 0; fi < KORD * FINC; ++fi) {
    const float fv = sm.feat[row][fi];
    #pragma unroll
    for (int q = 0; q < 4; ++q) {
      float4 wv = *reinterpret_cast<const float4*>(&sm.W[fi][fo8 * 16 + q * 4]);
      acc[q * 4]     = fmaf(fv, wv.x, acc[q * 4]);
      acc[q * 4 + 1] = fmaf(fv, wv.y, acc[q * 4 + 1]);
      acc[q * 4 + 2] = fmaf(fv, wv.z, acc[q * 4 + 2]);
      acc[q * 4 + 3] = fmaf(fv, wv.w, acc[q * 4 + 3]);
    }
  }

  const size_t obase = ((size_t)n * Mdim + rowbase + row) * FOUTC + fo8 * 16;
  #pragma unroll
  for (int q = 0; q < 4; ++q) {
    float4 ov;
    ov.x = fmaxf(acc[q * 4], 0.f);
    ov.y = fmaxf(acc[q * 4 + 1], 0.f);
    ov.z = fmaxf(acc[q * 4 + 2], 0.f);
    ov.w = fmaxf(acc[q * 4 + 3], 0.f);
    *reinterpret_cast<float4*>(&out[obase + q * 4]) = ov;
  }
}

extern "C" void kernel_launch(void* const* d_in, const int* in_sizes, int n_in,
                              void* d_out, int out_size, void* d_ws, size_t ws_size,
                              hipStream_t stream) {
  const float* x = (const float*)d_in[0];
  const float* L = (const float*)d_in[1];
  const float* W = (const float*)d_in[2];
  const float* B = (const float*)d_in[3];
  float* out = (float*)d_out;

  constexpr size_t LB_ELEMS = (size_t)Nb * Mdim * Mdim;
  const size_t need_full = LB_ELEMS * 2 + TSZ * 4 * 6 + TSZ * 2 * 6;  // ~152 MB
  const bool lb = ws_size >= need_full;

  char* p = (char*)d_ws;
  unsigned short* Lbuf = (unsigned short*)p;   // fragment-order bf16 L
  if (lb) p += LB_ELEMS * 2;
  float* xt_f = (float*)p;            p += TSZ * 4;
  float* T1f  = (float*)p;            p += TSZ * 4 * 5;
  unsigned short* xswz = (unsigned short*)p;  p += TSZ * 2;
  unsigned short* Tswz = (unsigned short*)p;

  float*          Tf[5] = {T1f, T1f + TSZ, T1f + 2 * TSZ, T1f + 3 * TSZ, T1f + 4 * TSZ};
  unsigned short* Ts[5] = {Tswz, Tswz + TSZ, Tswz + 2 * TSZ, Tswz + 3 * TSZ, Tswz + 4 * TSZ};

  dim3 blk(256);
  hipLaunchKernelGGL(prep_both, dim3(Nb * 17), blk, 0, stream, x, xt_f, xswz);

  if (lb) {
    hipLaunchKernelGGL(conv_pass1, dim3(Nb * 32), blk, 0, stream,
                       L, Lbuf, xswz, Tf[0], Ts[0]);
    dim3 grid(Nb * 64);
    hipLaunchKernelGGL((cheb_mfma<0, false, true>), grid, blk, 0, stream,
                       nullptr, Lbuf, Ts[0], xt_f, Tf[1], Ts[1]);
    hipLaunchKernelGGL((cheb_mfma<0, false, true>), grid, blk, 0, stream,
                       nullptr, Lbuf, Ts[1], Tf[0], Tf[2], Ts[2]);
    hipLaunchKernelGGL((cheb_mfma<0, false, true>), grid, blk, 0, stream,
                       nullptr, Lbuf, Ts[2], Tf[1], Tf[3], Ts[3]);
    hipLaunchKernelGGL(pass5_epi, dim3(Nb * 32), blk, 0, stream,
                       Lbuf, Ts[3], Tf[2], xt_f, T1f, W, B, out);
  } else {
    dim3 grid(Nb * 64);
    hipLaunchKernelGGL((cheb_mfma<2, true, true>), grid, blk, 0, stream,
                       L, nullptr, xswz, nullptr, Tf[0], Ts[0]);
    hipLaunchKernelGGL((cheb_mfma<2, false, true>), grid, blk, 0, stream,
                       L, nullptr, Ts[0], xt_f, Tf[1], Ts[1]);
    hipLaunchKernelGGL((cheb_mfma<2, false, true>), grid, blk, 0, stream,
                       L, nullptr, Ts[1], Tf[0], Tf[2], Ts[2]);
    hipLaunchKernelGGL((cheb_mfma<2, false, true>), grid, blk, 0, stream,
                       L, nullptr, Ts[2], Tf[1], Tf[3], Ts[3]);
    hipLaunchKernelGGL((cheb_mfma<2, false, false>), grid, blk, 0, stream,
                       L, nullptr, Ts[3], Tf[2], Tf[4], nullptr);
    hipLaunchKernelGGL(epilogue_kernel, dim3(Nb * (Mdim / EROWS)), blk, 0, stream,
                       xt_f, T1f, W, B, out);
  }
}